// Round 12
// baseline (949.854 us; speedup 1.0000x reference)
//
#include <hip/hip_runtime.h>
#include <cstdint>
#include <cstddef>

#define B_ 16
#define D_ 128
#define T_ 4500
#define N_ (B_*T_)      // 72000
#define K_ 1024
#define L_ 8
#define NRB 2250        // 32-row groups (exactly 72000/32)
#define NBLK 563        // 128-row blocks (562 full + 1 partial: 2 active waves)
#define DELTA 4.0e-4f   // covers f16 worst-case dot err (3.2e-4) + grid/pack (5e-5)
#define BSCALE 16384.0f // 2^14: lifts codebook out of f16-subnormal range (exact)

typedef _Float16 f16x8 __attribute__((ext_vector_type(8)));
typedef float f32x16 __attribute__((ext_vector_type(16)));

#define GLOBAL_AS __attribute__((address_space(1)))
#define LDS_AS    __attribute__((address_space(3)))

// ---------------- helpers ----------------
// insert x into sorted (p1<=p2<=p3), keep 3 smallest (3 VALU via med3)
__device__ __forceinline__ void ins3(float& p1, float& p2, float& p3, float x) {
  p3 = __builtin_amdgcn_fmed3f(p2, p3, x);
  p2 = __builtin_amdgcn_fmed3f(p1, p2, x);
  p1 = fminf(p1, x);
}
// merge two sorted triples, keep 3 smallest (7 VALU)
__device__ __forceinline__ void merge3(float& a1, float& a2, float& a3,
                                       float b1, float b2, float b3) {
  const float r3 = fminf(fminf(a3, b3), fminf(fmaxf(a2, b1), fmaxf(a1, b2)));
  const float r2 = fminf(fminf(fmaxf(a1, b1), a2), b2);
  const float r1 = fminf(a1, b1);
  a1 = r1; a2 = r2; a3 = r3;
}

// numpy pairwise_sum (n=128) of fl(x*x)
__device__ __forceinline__ float pairwise_sq_sum128(const float* __restrict__ x) {
  float r[8];
#pragma unroll
  for (int c = 0; c < 8; ++c) r[c] = __fmul_rn(x[c], x[c]);
#pragma unroll
  for (int i = 1; i < 16; ++i)
#pragma unroll
    for (int c = 0; c < 8; ++c)
      r[c] = __fadd_rn(r[c], __fmul_rn(x[8*i + c], x[8*i + c]));
  return __fadd_rn(__fadd_rn(__fadd_rn(r[0], r[1]), __fadd_rn(r[2], r[3])),
                   __fadd_rn(__fadd_rn(r[4], r[5]), __fadd_rn(r[6], r[7])));
}

__device__ __forceinline__ float tree8(const float* rc) {
  return __fadd_rn(__fadd_rn(__fadd_rn(rc[0], rc[1]), __fadd_rn(rc[2], rc[3])),
                   __fadd_rn(__fadd_rn(rc[4], rc[5]), __fadd_rn(rc[6], rc[7])));
}

// ---------------- transpose z [B][D][T] -> R [N][D] ----------------
__global__ __launch_bounds__(256)
void k_transpose_z(const float* __restrict__ z, float* __restrict__ R) {
  __shared__ float tile[32][33];
  const int t0 = blockIdx.x * 32;
  const int d0 = blockIdx.y * 32;
  const int b  = blockIdx.z;
  const int tid = threadIdx.x;
  {
    const int jj = tid & 31; const int ii0 = (tid >> 5) * 4;
#pragma unroll
    for (int r = 0; r < 4; ++r) {
      const int ii = ii0 + r;
      float v = 0.f;
      if (t0 + jj < T_) v = z[((size_t)(b*D_ + d0 + ii))*T_ + t0 + jj];
      tile[ii][jj] = v;
    }
  }
  __syncthreads();
  {
    const int ii = tid & 31; const int jj0 = (tid >> 5) * 4;
#pragma unroll
    for (int r = 0; r < 4; ++r) {
      const int jj = jj0 + r;
      if (t0 + jj < T_)
        R[((size_t)(b*T_ + t0 + jj))*D_ + d0 + ii] = tile[ii][jj];
    }
  }
}

// ---------------- transpose cb [L][K][D] -> cbT [L][D][K] ----------------
__global__ __launch_bounds__(256)
void k_transpose_cb(const float* __restrict__ cb, float* __restrict__ cbT) {
  __shared__ float tile[32][33];
  const int j0 = blockIdx.x * 32;
  const int d0 = blockIdx.y * 32;
  const int l  = blockIdx.z;
  const int tid = threadIdx.x;
  {
    const int dd = tid & 31; const int jj0 = (tid >> 5) * 4;
#pragma unroll
    for (int r = 0; r < 4; ++r)
      tile[jj0 + r][dd] = cb[((size_t)(l*K_ + j0 + jj0 + r))*D_ + d0 + dd];
  }
  __syncthreads();
  {
    const int jj = tid & 31; const int dd0 = (tid >> 5) * 4;
#pragma unroll
    for (int r = 0; r < 4; ++r)
      cbT[((size_t)(l*D_ + d0 + dd0 + r))*K_ + j0 + jj] = tile[jj][dd0 + r];
  }
}

// ---------------- per-code squared norms (numpy pairwise) ----------------
__global__ __launch_bounds__(256)
void k_y2(const float* __restrict__ cb, float* __restrict__ y2f) {
  const int row = blockIdx.x * 256 + threadIdx.x;
  if (row >= L_ * K_) return;
  y2f[row] = pairwise_sq_sum128(&cb[(size_t)row * D_]);
}

// ---------------- codebook -> fragment-ready f16 (scaled by 2^14) ----------------
// Bpk[l][colblk(32)][s(8)][lane(64)] : uint4 (8 f16)
// lane: col = colblk*32 + (lane&31), k = 16s + 8*(lane>>5) + 0..7
__global__ __launch_bounds__(256)
void k_prep_b(const float* __restrict__ cb, uint4* __restrict__ Bpk) {
  const int tid = threadIdx.x;
  const int gw = blockIdx.x*4 + (tid >> 6);   // 0..255
  const int l = gw >> 5, cbk = gw & 31;
  const int lane = tid & 63, l31 = lane & 31, lh = lane >> 5;
  const int col = cbk*32 + l31;
  const float* src = cb + ((size_t)l*K_ + col)*D_ + lh*8;
  uint4* dst = Bpk + (size_t)l*16384 + (size_t)cbk*512;
#pragma unroll
  for (int s = 0; s < 8; ++s) {
    const float4 va = *(const float4*)(src + s*16);
    const float4 vb = *(const float4*)(src + s*16 + 4);
    f16x8 h;
    h[0] = (_Float16)(va.x * BSCALE); h[1] = (_Float16)(va.y * BSCALE);
    h[2] = (_Float16)(va.z * BSCALE); h[3] = (_Float16)(va.w * BSCALE);
    h[4] = (_Float16)(vb.x * BSCALE); h[5] = (_Float16)(vb.y * BSCALE);
    h[6] = (_Float16)(vb.z * BSCALE); h[7] = (_Float16)(vb.w * BSCALE);
    dst[s*64 + lane] = __builtin_bit_cast(uint4, h);
  }
}

// ---------------- x2 init (layer 0) ----------------
__global__ __launch_bounds__(256)
void k_x2g(const float* __restrict__ R, float* __restrict__ x2) {
  const int tid = threadIdx.x;
  const int rowblk = blockIdx.x*4 + (tid >> 6);
  if (rowblk >= NRB) return;
  const int lane = tid & 63, l31 = lane & 31, lh = lane >> 5;
  const int row = rowblk*32 + l31;
  const float* rr = R + (size_t)row*D_ + lh*8;
  float rc[8] = {0,0,0,0,0,0,0,0};
#pragma unroll
  for (int s = 0; s < 8; ++s) {
    const float4 va = *(const float4*)(rr + s*16);
    const float4 vb = *(const float4*)(rr + s*16 + 4);
    const float rn[8] = {va.x, va.y, va.z, va.w, vb.x, vb.y, vb.z, vb.w};
#pragma unroll
    for (int c = 0; c < 8; ++c) {
      const float sq = __fmul_rn(rn[c], rn[c]);
      const float pv = __shfl_xor(sq, 32);
      rc[c] = __fadd_rn(rc[c], sq);
      rc[c] = __fadd_rn(rc[c], pv);
    }
  }
  if (lh == 0) x2[row] = tree8(rc);
}

// ---------------- fused layer kernel: f16 screen + exact fixups + update ----------------
// Phase 1: single-pass f16 MFMA screen (64-code chunks, 16 KB, LDS dbuf,
//          counted vmcnt). u = fl(y2 - 2^-13*accS) == fl(y2 - 2*dot_f16).
// Phase 2: per-wave exact f32 fixups (A: pair rescore; B: full scan).
// Phase 3: residual update + x2 + codes + loss.
__global__ __launch_bounds__(256, 3)
void k_layer(float* __restrict__ R, const uint4* __restrict__ Bpk_l,
             const float* __restrict__ y2l, const float* __restrict__ cbl,
             const float* __restrict__ cbTl, float* __restrict__ x2,
             float* __restrict__ out_codes, float* __restrict__ lossp)
{
  __shared__ uint4 Bs[2][1024];     // 32 KB double buffer (64-code f16 chunks)
  __shared__ float y2s[K_];         // 4 KB
  __shared__ int2  rec[4][32];      // 1 KB  per-wave row decisions
  __shared__ float rs[4][128];      // 2 KB  mode-B row staging
  const int tid = threadIdx.x;
  const int w = tid >> 6;
  const int lane = tid & 63, l31 = lane & 31, lh = lane >> 5;
  const int n0w = blockIdx.x*128 + w*32;
  const bool wactive = (n0w < N_);          // whole-wave granularity (N_%32==0)
  const int rbase = wactive ? n0w : 0;

#define STAGE(buf_, ch_) { \
    const uint4* sp_ = Bpk_l + (size_t)(ch_)*1024 + tid; \
    LDS_AS uint4* dp_ = (LDS_AS uint4*)&Bs[buf_][tid]; \
    _Pragma("unroll") \
    for (int i_ = 0; i_ < 4; ++i_) \
      __builtin_amdgcn_global_load_lds((const GLOBAL_AS void*)(sp_ + i_*256), \
                                       (LDS_AS void*)(dp_ + i_*256), 16, 0, 0); }

  STAGE(0, 0)

  // y2 -> LDS
  {
    const float4 yv = *(const float4*)&y2l[tid*4];
    *(float4*)&y2s[tid*4] = yv;
  }

  // A fragments: f32 -> f16 (RNE), unscaled; k-map matches k_prep_b
  f16x8 ah[8];
  {
    const float* rr = R + ((size_t)rbase + l31)*D_ + lh*8;
    float4 ra[8], rb[8];
#pragma unroll
    for (int s = 0; s < 8; ++s) {
      ra[s] = *(const float4*)(rr + s*16);
      rb[s] = *(const float4*)(rr + s*16 + 4);
    }
#pragma unroll
    for (int s = 0; s < 8; ++s) {
      f16x8 h;
      h[0] = (_Float16)ra[s].x; h[1] = (_Float16)ra[s].y;
      h[2] = (_Float16)ra[s].z; h[3] = (_Float16)ra[s].w;
      h[4] = (_Float16)rb[s].x; h[5] = (_Float16)rb[s].y;
      h[6] = (_Float16)rb[s].z; h[7] = (_Float16)rb[s].w;
      ah[s] = h;
    }
  }

  const float PINIT = __uint_as_float(0x7F7FFC00u);
  float p1[16], p2[16], p3[16];
#pragma unroll
  for (int r = 0; r < 16; ++r) { p1[r] = PINIT; p2[r] = PINIT; p3[r] = PINIT; }

  __syncthreads();   // prologue: y2s visible, chunk 0 landed

  for (int ch = 0; ch < 16; ++ch) {
    const int buf = ch & 1;
    if (ch < 15) {
      STAGE(buf ^ 1, ch + 1)
      asm volatile("s_waitcnt vmcnt(4)" ::: "memory");   // ch landed, ch+1 in flight
    } else {
      asm volatile("s_waitcnt vmcnt(0)" ::: "memory");
    }
    __builtin_amdgcn_s_barrier();
    asm volatile("" ::: "memory");

    f32x16 acc0, acc1;
#pragma unroll
    for (int r = 0; r < 16; ++r) { acc0[r] = 0.f; acc1[r] = 0.f; }
    const uint4* bb = &Bs[buf][0];
    __builtin_amdgcn_s_setprio(1);
#pragma unroll
    for (int s = 0; s < 8; ++s) {
      const f16x8 b0 = __builtin_bit_cast(f16x8, bb[s*64 + lane]);
      const f16x8 b1 = __builtin_bit_cast(f16x8, bb[512 + s*64 + lane]);
      acc0 = __builtin_amdgcn_mfma_f32_32x32x16_f16(ah[s], b0, acc0, 0, 0, 0);
      acc1 = __builtin_amdgcn_mfma_f32_32x32x16_f16(ah[s], b1, acc1, 0, 0, 0);
    }
    __builtin_amdgcn_s_setprio(0);
    const float y2a = y2s[ch*64 + l31];
    const float y2b = y2s[ch*64 + 32 + l31];
    const unsigned ia = (unsigned)(ch*64 + l31);
    const unsigned ib = ia + 32;
#pragma unroll
    for (int r = 0; r < 16; ++r) {
      // u = fl(y2 - 2*dot): acc is scaled by 2^14, -2^-13*acc == -2*dot exactly
      const float d0 = fmaf(-0x1p-13f, acc0[r], y2a);
      const float d1 = fmaf(-0x1p-13f, acc1[r], y2b);
      const float x0 = __uint_as_float((__float_as_uint(d0) & ~1023u) | ia);
      const float x1 = __uint_as_float((__float_as_uint(d1) & ~1023u) | ib);
      ins3(p1[r], p2[r], p3[r], x0);
      ins3(p1[r], p2[r], p3[r], x1);
    }
    asm volatile("" ::: "memory");
    __builtin_amdgcn_s_barrier();
  }
#undef STAGE

  // per-wave finalize: butterfly, write decisions to rec
#pragma unroll
  for (int r = 0; r < 16; ++r) {
#pragma unroll
    for (int off = 1; off < 32; off <<= 1) {
      const float b1 = __shfl_xor(p1[r], off);
      const float b2 = __shfl_xor(p2[r], off);
      const float b3 = __shfl_xor(p3[r], off);
      merge3(p1[r], p2[r], p3[r], b1, b2, b3);
    }
    if (l31 == 0) {
      const int ri = (r&3) + 8*(r>>2) + 4*lh;   // row index within wave, 0..31
      int flags = 0;
      if (p3[r] - p1[r] <= DELTA) flags = 2;         // >=3 candidates: full scan
      else if (p2[r] - p1[r] <= DELTA) flags = 1;    // exactly 2 candidates
      rec[w][ri] = make_int2((int)(__float_as_uint(p1[r]) & 1023u) | (flags << 12),
                             (int)(__float_as_uint(p2[r]) & 1023u));
    }
  }
  asm volatile("s_waitcnt lgkmcnt(0)" ::: "memory");

  // ---- phase 2a: mode A — exact pair rescore, one lane per flagged row ----
  {
    bool doA = false; int cA1 = 0, cA2 = 0;
    if (wactive && lane < 32) {
      const int2 mr = rec[w][lane];
      if ((mr.x >> 12) == 1) { doA = true; cA1 = mr.x & 1023; cA2 = mr.y; }
    }
    if (doA) {
      const int n = rbase + lane;
      const float* xr = &R[(size_t)n*D_];
      const float* pa = &cbl[(size_t)cA1*D_];
      const float* pb = &cbl[(size_t)cA2*D_];
      float s1 = 0.f, s2 = 0.f;
#pragma unroll
      for (int k = 0; k < D_; k += 4) {   // strict ascending-k BLAS chain
        const float4 x = *(const float4*)(xr + k);
        const float4 A = *(const float4*)(pa + k);
        const float4 Bv = *(const float4*)(pb + k);
        s1 = fmaf(x.x, A.x, s1);  s1 = fmaf(x.y, A.y, s1);
        s1 = fmaf(x.z, A.z, s1);  s1 = fmaf(x.w, A.w, s1);
        s2 = fmaf(x.x, Bv.x, s2); s2 = fmaf(x.y, Bv.y, s2);
        s2 = fmaf(x.z, Bv.z, s2); s2 = fmaf(x.w, Bv.w, s2);
      }
      const float x2n = x2[n];
      const float d1 = __fsub_rn(__fadd_rn(x2n, y2l[cA1]), __fmul_rn(2.f, s1));
      const float d2 = __fsub_rn(__fadd_rn(x2n, y2l[cA2]), __fmul_rn(2.f, s2));
      const bool take2 = (d2 < d1) || (d2 == d1 && cA2 < cA1);
      rec[w][lane] = make_int2(take2 ? cA2 : cA1, 0);   // final, flags cleared
    }
    asm volatile("s_waitcnt lgkmcnt(0)" ::: "memory");
  }

  // ---- phase 2b: mode B — wave-cooperative exact full scan (rare rows) ----
  if (wactive) {
    for (int ri = 0; ri < 32; ++ri) {
      const int2 rr2 = rec[w][ri];          // broadcast read
      if ((rr2.x >> 12) != 2) continue;
      const int n = rbase + ri;
      const float2 t = *(const float2*)&R[(size_t)n*D_ + lane*2];
      rs[w][lane*2] = t.x; rs[w][lane*2+1] = t.y;
      asm volatile("s_waitcnt lgkmcnt(0)" ::: "memory");
      const float x2n = x2[n];
      float acc[16];
#pragma unroll
      for (int q = 0; q < 16; ++q) acc[q] = 0.f;
      for (int k = 0; k < 128; ++k) {       // ascending k: exact BLAS chain per j
        const float rv = rs[w][k];
        const float* cr = cbTl + (size_t)k*K_ + lane;
#pragma unroll
        for (int q = 0; q < 16; ++q)
          acc[q] = fmaf(rv, cr[q*64], acc[q]);
      }
      float vb = 3.0e38f; int jb = 0;
#pragma unroll
      for (int q = 0; q < 16; ++q) {
        const int j = q*64 + lane;
        const float dv = fmaf(-2.f, acc[q], __fadd_rn(x2n, y2l[j]));
        if (dv < vb) { vb = dv; jb = j; }   // j ascends with q: ties keep lower
      }
#pragma unroll
      for (int off = 1; off < 64; off <<= 1) {
        const float bv = __shfl_xor(vb, off);
        const int   bj = __shfl_xor(jb, off);
        if (bv < vb || (bv == vb && bj < jb)) { vb = bv; jb = bj; }
      }
      if (lane == 0) rec[w][ri] = make_int2(jb, 0);
      asm volatile("s_waitcnt lgkmcnt(0)" ::: "memory");  // rs + rec ordering
    }
  }

  // ---- phase 3: residual update + x2 + codes + loss ----
  float ss = 0.f;
  if (wactive) {
    const int row = rbase + l31;
    const int code = rec[w][l31].x & 1023;
    float* rr = R + (size_t)row*D_ + lh*8;
    const float* cr = cbl + (size_t)code*D_ + lh*8;
    float4 xa[8], xb[8], qa[8], qb[8];
#pragma unroll
    for (int s = 0; s < 8; ++s) {
      xa[s] = *(const float4*)(rr + s*16);
      xb[s] = *(const float4*)(rr + s*16 + 4);
      qa[s] = *(const float4*)(cr + s*16);
      qb[s] = *(const float4*)(cr + s*16 + 4);
    }
    float rc[8] = {0,0,0,0,0,0,0,0};
#pragma unroll
    for (int s = 0; s < 8; ++s) {
      float rn[8];
      rn[0] = __fsub_rn(xa[s].x, qa[s].x); rn[1] = __fsub_rn(xa[s].y, qa[s].y);
      rn[2] = __fsub_rn(xa[s].z, qa[s].z); rn[3] = __fsub_rn(xa[s].w, qa[s].w);
      rn[4] = __fsub_rn(xb[s].x, qb[s].x); rn[5] = __fsub_rn(xb[s].y, qb[s].y);
      rn[6] = __fsub_rn(xb[s].z, qb[s].z); rn[7] = __fsub_rn(xb[s].w, qb[s].w);
      *(float4*)(rr + s*16)     = make_float4(rn[0], rn[1], rn[2], rn[3]);
      *(float4*)(rr + s*16 + 4) = make_float4(rn[4], rn[5], rn[6], rn[7]);
#pragma unroll
      for (int c = 0; c < 8; ++c) ss = fmaf(rn[c], rn[c], ss);
      // numpy pairwise x2: lane lh=0 owns i=2s, partner i=2s+1
#pragma unroll
      for (int c = 0; c < 8; ++c) {
        const float sq = __fmul_rn(rn[c], rn[c]);
        const float pv = __shfl_xor(sq, 32);
        rc[c] = __fadd_rn(rc[c], sq);
        rc[c] = __fadd_rn(rc[c], pv);
      }
    }
    if (lh == 0) {
      x2[row] = tree8(rc);
      out_codes[row] = (float)code;
    }
  }
#pragma unroll
  for (int off = 1; off < 64; off <<= 1) ss += __shfl_xor(ss, off);
  if (wactive && lane == 0) atomicAdd(lossp, ss);
}

// ---------------- finalize ----------------
__global__ __launch_bounds__(256)
void k_finalize_quant(const float* __restrict__ z, const float* __restrict__ R,
                      float* __restrict__ out) {
  __shared__ float tile[32][33];
  const int t0 = blockIdx.x * 32;
  const int d0 = blockIdx.y * 32;
  const int b  = blockIdx.z;
  const int tid = threadIdx.x;
  {
    const int ii = tid & 31; const int jj0 = (tid >> 5) * 4;
#pragma unroll
    for (int r = 0; r < 4; ++r) {
      const int jj = jj0 + r;
      tile[ii][jj] = (t0 + jj < T_) ? R[((size_t)(b*T_ + t0 + jj))*D_ + d0 + ii] : 0.f;
    }
  }
  __syncthreads();
  {
    const int jj = tid & 31; const int ii0 = (tid >> 5) * 4;
#pragma unroll
    for (int r = 0; r < 4; ++r) {
      const int ii = ii0 + r;
      if (t0 + jj < T_) {
        const size_t gi = ((size_t)(b*D_ + d0 + ii))*T_ + t0 + jj;
        out[gi] = __fsub_rn(z[gi], tile[ii][jj]);
      }
    }
  }
}

__global__ void k_finalize_loss(const float* __restrict__ lossp, float* __restrict__ out2) {
  const float lv = (float)((double)lossp[0] / (double)((size_t)N_ * D_));
  out2[0] = lv;
  out2[1] = lv;
}

// ---------------- host launch ----------------
extern "C" void kernel_launch(void* const* d_in, const int* in_sizes, int n_in,
                              void* d_out, int out_size, void* d_ws, size_t ws_size,
                              hipStream_t stream) {
  const float* z  = (const float*)d_in[0];
  const float* cb = (const float*)d_in[1];
  float* out = (float*)d_out;

  char* ws = (char*)d_ws;
  const size_t OFF_R    = 0;
  const size_t OFF_BPK  = OFF_R   + (size_t)N_ * D_ * 4;        // 36,864,000
  const size_t OFF_CBT  = OFF_BPK + (size_t)L_ * 16384 * 16;    // 38,961,152
  const size_t OFF_Y2   = OFF_CBT + (size_t)L_ * D_ * K_ * 4;   // 43,155,456
  const size_t OFF_X2   = OFF_Y2  + (size_t)L_ * K_ * 4;        // 43,188,224
  const size_t OFF_LOSS = OFF_X2  + (size_t)N_ * 4;             // 43,476,224

  float* R     = (float*)(ws + OFF_R);
  uint4* Bpk   = (uint4*)(ws + OFF_BPK);
  float* cbT   = (float*)(ws + OFF_CBT);
  float* y2f   = (float*)(ws + OFF_Y2);
  float* x2    = (float*)(ws + OFF_X2);
  float* lossp = (float*)(ws + OFF_LOSS);

  hipMemsetAsync(lossp, 0, 4, stream);

  k_transpose_z<<<dim3((T_ + 31)/32, D_/32, B_), 256, 0, stream>>>(z, R);
  k_transpose_cb<<<dim3(K_/32, D_/32, L_), 256, 0, stream>>>(cb, cbT);
  k_y2<<<(L_ * K_)/256, 256, 0, stream>>>(cb, y2f);
  k_prep_b<<<64, 256, 0, stream>>>(cb, Bpk);
  k_x2g<<<563, 256, 0, stream>>>(R, x2);

  for (int l = 0; l < L_; ++l) {
    k_layer<<<NBLK, 256, 0, stream>>>(
        R,
        Bpk + (size_t)l * 16384,
        y2f + (size_t)l * K_,
        cb  + (size_t)l * K_ * D_,
        cbT + (size_t)l * D_ * K_,
        x2,
        out + (size_t)N_ * D_ + (size_t)l * N_,
        lossp);
  }

  k_finalize_quant<<<dim3((T_ + 31)/32, D_/32, B_), 256, 0, stream>>>(z, R, out);
  k_finalize_loss<<<1, 1, 0, stream>>>(lossp, out + (size_t)N_ * D_ + (size_t)L_ * N_);
}

// Round 13
// 791.545 us; speedup vs baseline: 1.2000x; 1.2000x over previous
//
#include <hip/hip_runtime.h>
#include <cstdint>
#include <cstddef>

#define B_ 16
#define D_ 128
#define T_ 4500
#define N_ (B_*T_)      // 72000
#define K_ 1024
#define L_ 8
#define NBLK 563        // 128-row blocks (562 full + 1 partial: 2 active waves)
#define DELTA 4.0e-4f   // covers f16 worst-case dot err (3.2e-4) + grid/pack (5e-5)
#define BSCALE 16384.0f // 2^14: lifts codebook out of f16-subnormal range (exact)

typedef _Float16 f16x8 __attribute__((ext_vector_type(8)));
typedef float f32x16 __attribute__((ext_vector_type(16)));

#define GLOBAL_AS __attribute__((address_space(1)))
#define LDS_AS    __attribute__((address_space(3)))

// ---------------- helpers ----------------
// insert x into sorted (p1<=p2<=p3), keep 3 smallest (3 VALU via med3)
__device__ __forceinline__ void ins3(float& p1, float& p2, float& p3, float x) {
  p3 = __builtin_amdgcn_fmed3f(p2, p3, x);
  p2 = __builtin_amdgcn_fmed3f(p1, p2, x);
  p1 = fminf(p1, x);
}
// merge two sorted triples, keep 3 smallest (7 VALU)
__device__ __forceinline__ void merge3(float& a1, float& a2, float& a3,
                                       float b1, float b2, float b3) {
  const float r3 = fminf(fminf(a3, b3), fminf(fmaxf(a2, b1), fmaxf(a1, b2)));
  const float r2 = fminf(fminf(fmaxf(a1, b1), a2), b2);
  const float r1 = fminf(a1, b1);
  a1 = r1; a2 = r2; a3 = r3;
}

// numpy pairwise_sum (n=128) of fl(x*x)
__device__ __forceinline__ float pairwise_sq_sum128(const float* __restrict__ x) {
  float r[8];
#pragma unroll
  for (int c = 0; c < 8; ++c) r[c] = __fmul_rn(x[c], x[c]);
#pragma unroll
  for (int i = 1; i < 16; ++i)
#pragma unroll
    for (int c = 0; c < 8; ++c)
      r[c] = __fadd_rn(r[c], __fmul_rn(x[8*i + c], x[8*i + c]));
  return __fadd_rn(__fadd_rn(__fadd_rn(r[0], r[1]), __fadd_rn(r[2], r[3])),
                   __fadd_rn(__fadd_rn(r[4], r[5]), __fadd_rn(r[6], r[7])));
}

__device__ __forceinline__ float tree8(const float* rc) {
  return __fadd_rn(__fadd_rn(__fadd_rn(rc[0], rc[1]), __fadd_rn(rc[2], rc[3])),
                   __fadd_rn(__fadd_rn(rc[4], rc[5]), __fadd_rn(rc[6], rc[7])));
}

// ---------------- transpose z [B][D][T] -> R [N][D] ----------------
__global__ __launch_bounds__(256)
void k_transpose_z(const float* __restrict__ z, float* __restrict__ R) {
  __shared__ float tile[32][33];
  const int t0 = blockIdx.x * 32;
  const int d0 = blockIdx.y * 32;
  const int b  = blockIdx.z;
  const int tid = threadIdx.x;
  {
    const int jj = tid & 31; const int ii0 = (tid >> 5) * 4;
#pragma unroll
    for (int r = 0; r < 4; ++r) {
      const int ii = ii0 + r;
      float v = 0.f;
      if (t0 + jj < T_) v = z[((size_t)(b*D_ + d0 + ii))*T_ + t0 + jj];
      tile[ii][jj] = v;
    }
  }
  __syncthreads();
  {
    const int ii = tid & 31; const int jj0 = (tid >> 5) * 4;
#pragma unroll
    for (int r = 0; r < 4; ++r) {
      const int jj = jj0 + r;
      if (t0 + jj < T_)
        R[((size_t)(b*T_ + t0 + jj))*D_ + d0 + ii] = tile[ii][jj];
    }
  }
}

// ---------------- transpose cb [L][K][D] -> cbT [L][D][K] ----------------
__global__ __launch_bounds__(256)
void k_transpose_cb(const float* __restrict__ cb, float* __restrict__ cbT) {
  __shared__ float tile[32][33];
  const int j0 = blockIdx.x * 32;
  const int d0 = blockIdx.y * 32;
  const int l  = blockIdx.z;
  const int tid = threadIdx.x;
  {
    const int dd = tid & 31; const int jj0 = (tid >> 5) * 4;
#pragma unroll
    for (int r = 0; r < 4; ++r)
      tile[jj0 + r][dd] = cb[((size_t)(l*K_ + j0 + jj0 + r))*D_ + d0 + dd];
  }
  __syncthreads();
  {
    const int jj = tid & 31; const int dd0 = (tid >> 5) * 4;
#pragma unroll
    for (int r = 0; r < 4; ++r)
      cbT[((size_t)(l*D_ + d0 + dd0 + r))*K_ + j0 + jj] = tile[jj][dd0 + r];
  }
}

// ---------------- per-code squared norms (numpy pairwise) ----------------
__global__ __launch_bounds__(256)
void k_y2(const float* __restrict__ cb, float* __restrict__ y2f) {
  const int row = blockIdx.x * 256 + threadIdx.x;
  if (row >= L_ * K_) return;
  y2f[row] = pairwise_sq_sum128(&cb[(size_t)row * D_]);
}

// ---------------- codebook -> fragment-ready f16 (scaled by 2^14) ----------------
// Bpk[l][colblk(32)][s(8)][lane(64)] : uint4 (8 f16)
// lane: col = colblk*32 + (lane&31), k = 16s + 8*(lane>>5) + 0..7
__global__ __launch_bounds__(256)
void k_prep_b(const float* __restrict__ cb, uint4* __restrict__ Bpk) {
  const int tid = threadIdx.x;
  const int gw = blockIdx.x*4 + (tid >> 6);   // 0..255
  const int l = gw >> 5, cbk = gw & 31;
  const int lane = tid & 63, l31 = lane & 31, lh = lane >> 5;
  const int col = cbk*32 + l31;
  const float* src = cb + ((size_t)l*K_ + col)*D_ + lh*8;
  uint4* dst = Bpk + (size_t)l*16384 + (size_t)cbk*512;
#pragma unroll
  for (int s = 0; s < 8; ++s) {
    const float4 va = *(const float4*)(src + s*16);
    const float4 vb = *(const float4*)(src + s*16 + 4);
    f16x8 h;
    h[0] = (_Float16)(va.x * BSCALE); h[1] = (_Float16)(va.y * BSCALE);
    h[2] = (_Float16)(va.z * BSCALE); h[3] = (_Float16)(va.w * BSCALE);
    h[4] = (_Float16)(vb.x * BSCALE); h[5] = (_Float16)(vb.y * BSCALE);
    h[6] = (_Float16)(vb.z * BSCALE); h[7] = (_Float16)(vb.w * BSCALE);
    dst[s*64 + lane] = __builtin_bit_cast(uint4, h);
  }
}

// ---------------- mega-fused RVQ: all 8 layers, residual in registers ----------------
// Block = 128 rows; wave w owns rows blk*128+w*32..+32. Per layer:
//   phase 1: f16 MFMA screen (64-code chunks, LDS dbuf, counted vmcnt)
//   phase 2: exact f32 fixups (A: pair rescore via shfl partner-half;
//            B: full scan via register->LDS row staging)
//   phase 3: in-register residual update + x2 + codes + loss accumulation
// R read once at start, written once at end. No inter-layer HBM round trips.
__global__ __launch_bounds__(256, 2)
void k_rvq(float* __restrict__ R, const uint4* __restrict__ Bpk,
           const float* __restrict__ y2f, const float* __restrict__ cb,
           const float* __restrict__ cbT,
           float* __restrict__ out_codes, float* __restrict__ lossp)
{
  __shared__ uint4 Bs[2][1024];     // 32 KB double buffer (64-code f16 chunks)
  __shared__ float y2s[K_];         // 4 KB (restaged per layer)
  __shared__ int2  rec[4][32];      // per-wave row decisions
  __shared__ float rs[4][128];      // mode-B row staging
  __shared__ float x2w[4][32];      // per-wave x2
  const int tid = threadIdx.x;
  const int w = tid >> 6;
  const int lane = tid & 63, l31 = lane & 31, lh = lane >> 5;
  const int n0w = blockIdx.x*128 + w*32;
  const bool wactive = (n0w < N_);          // whole-wave granularity
  const int rbase = wactive ? n0w : 0;
  const int row = rbase + l31;
  const bool hihalf = (lh != 0);

  // ---- load residual into registers (only R read of the whole op) ----
  float4 xa[8], xb[8];
  {
    const float* rr = R + (size_t)row*D_ + lh*8;
#pragma unroll
    for (int s = 0; s < 8; ++s) {
      xa[s] = *(const float4*)(rr + s*16);
      xb[s] = *(const float4*)(rr + s*16 + 4);
    }
  }
  // ---- x2 init (numpy pairwise, lane lh=0 owns i=2s, partner i=2s+1) ----
  {
    float rc[8] = {0,0,0,0,0,0,0,0};
#pragma unroll
    for (int s = 0; s < 8; ++s) {
      const float rn[8] = {xa[s].x, xa[s].y, xa[s].z, xa[s].w,
                           xb[s].x, xb[s].y, xb[s].z, xb[s].w};
#pragma unroll
      for (int c = 0; c < 8; ++c) {
        const float sq = __fmul_rn(rn[c], rn[c]);
        const float pv = __shfl_xor(sq, 32);
        rc[c] = __fadd_rn(rc[c], sq);
        rc[c] = __fadd_rn(rc[c], pv);
      }
    }
    if (lh == 0) x2w[w][l31] = tree8(rc);
  }

  float lsum = 0.f;
  const float PINIT = __uint_as_float(0x7F7FFC00u);

  for (int l = 0; l < L_; ++l) {
    const uint4* Bpk_l = Bpk + (size_t)l*16384;
    const float* y2l  = y2f + (size_t)l*K_;
    const float* cbl  = cb  + (size_t)l*K_*D_;
    const float* cbTl = cbT + (size_t)l*D_*K_;

    __syncthreads();   // Bs/y2s free from previous layer, all waves converged

#define STAGE(buf_, ch_) { \
    const uint4* sp_ = Bpk_l + (size_t)(ch_)*1024 + tid; \
    LDS_AS uint4* dp_ = (LDS_AS uint4*)&Bs[buf_][tid]; \
    _Pragma("unroll") \
    for (int i_ = 0; i_ < 4; ++i_) \
      __builtin_amdgcn_global_load_lds((const GLOBAL_AS void*)(sp_ + i_*256), \
                                       (LDS_AS void*)(dp_ + i_*256), 16, 0, 0); }

    STAGE(0, 0)
    {
      const float4 yv = *(const float4*)&y2l[tid*4];
      *(float4*)&y2s[tid*4] = yv;
    }

    // pack A fragments from registers (k-map matches k_prep_b)
    f16x8 ah[8];
#pragma unroll
    for (int s = 0; s < 8; ++s) {
      f16x8 h;
      h[0] = (_Float16)xa[s].x; h[1] = (_Float16)xa[s].y;
      h[2] = (_Float16)xa[s].z; h[3] = (_Float16)xa[s].w;
      h[4] = (_Float16)xb[s].x; h[5] = (_Float16)xb[s].y;
      h[6] = (_Float16)xb[s].z; h[7] = (_Float16)xb[s].w;
      ah[s] = h;
    }

    float p1[16], p2[16], p3[16];
#pragma unroll
    for (int r = 0; r < 16; ++r) { p1[r] = PINIT; p2[r] = PINIT; p3[r] = PINIT; }

    __syncthreads();   // y2s + chunk 0 landed (syncthreads drains vm+lgkm)

    for (int ch = 0; ch < 16; ++ch) {
      const int buf = ch & 1;
      if (ch < 15) {
        STAGE(buf ^ 1, ch + 1)
        asm volatile("s_waitcnt vmcnt(4)" ::: "memory");   // ch landed, ch+1 in flight
      } else {
        asm volatile("s_waitcnt vmcnt(0)" ::: "memory");
      }
      __builtin_amdgcn_s_barrier();
      asm volatile("" ::: "memory");

      f32x16 acc0, acc1;
#pragma unroll
      for (int r = 0; r < 16; ++r) { acc0[r] = 0.f; acc1[r] = 0.f; }
      const uint4* bb = &Bs[buf][0];
      __builtin_amdgcn_s_setprio(1);
#pragma unroll
      for (int s = 0; s < 8; ++s) {
        const f16x8 b0 = __builtin_bit_cast(f16x8, bb[s*64 + lane]);
        const f16x8 b1 = __builtin_bit_cast(f16x8, bb[512 + s*64 + lane]);
        acc0 = __builtin_amdgcn_mfma_f32_32x32x16_f16(ah[s], b0, acc0, 0, 0, 0);
        acc1 = __builtin_amdgcn_mfma_f32_32x32x16_f16(ah[s], b1, acc1, 0, 0, 0);
      }
      __builtin_amdgcn_s_setprio(0);
      const float y2a = y2s[ch*64 + l31];
      const float y2b = y2s[ch*64 + 32 + l31];
      const unsigned ia = (unsigned)(ch*64 + l31);
      const unsigned ib = ia + 32;
#pragma unroll
      for (int r = 0; r < 16; ++r) {
        const float d0 = fmaf(-0x1p-13f, acc0[r], y2a);   // == fl(y2 - 2*dot)
        const float d1 = fmaf(-0x1p-13f, acc1[r], y2b);
        const float x0 = __uint_as_float((__float_as_uint(d0) & ~1023u) | ia);
        const float x1 = __uint_as_float((__float_as_uint(d1) & ~1023u) | ib);
        ins3(p1[r], p2[r], p3[r], x0);
        ins3(p1[r], p2[r], p3[r], x1);
      }
      asm volatile("" ::: "memory");
      __builtin_amdgcn_s_barrier();
    }
#undef STAGE

    // per-wave finalize: butterfly, write decisions to rec
#pragma unroll
    for (int r = 0; r < 16; ++r) {
#pragma unroll
      for (int off = 1; off < 32; off <<= 1) {
        const float b1 = __shfl_xor(p1[r], off);
        const float b2 = __shfl_xor(p2[r], off);
        const float b3 = __shfl_xor(p3[r], off);
        merge3(p1[r], p2[r], p3[r], b1, b2, b3);
      }
      if (l31 == 0) {
        const int ri = (r&3) + 8*(r>>2) + 4*lh;   // row index within wave
        int flags = 0;
        if (p3[r] - p1[r] <= DELTA) flags = 2;         // >=3 candidates
        else if (p2[r] - p1[r] <= DELTA) flags = 1;    // exactly 2 candidates
        rec[w][ri] = make_int2((int)(__float_as_uint(p1[r]) & 1023u) | (flags << 12),
                               (int)(__float_as_uint(p2[r]) & 1023u));
      }
    }
    asm volatile("s_waitcnt lgkmcnt(0)" ::: "memory");

    // ---- phase 2a: mode A — exact pair rescore from registers ----
    {
      const int2 mr = rec[w][l31];
      const bool doA = wactive && ((mr.x >> 12) == 1);
      const int cA1 = mr.x & 1023, cA2 = mr.y & 1023;
      const float* pa = cbl + (size_t)cA1*D_;
      const float* pb = cbl + (size_t)cA2*D_;
      float s1 = 0.f, s2 = 0.f;
#pragma unroll
      for (int s = 0; s < 8; ++s) {
        const float o0 = xa[s].x, o1 = xa[s].y, o2 = xa[s].z, o3 = xa[s].w;
        const float o4 = xb[s].x, o5 = xb[s].y, o6 = xb[s].z, o7 = xb[s].w;
        const float q0 = __shfl_xor(o0, 32), q1 = __shfl_xor(o1, 32);
        const float q2 = __shfl_xor(o2, 32), q3 = __shfl_xor(o3, 32);
        const float q4 = __shfl_xor(o4, 32), q5 = __shfl_xor(o5, 32);
        const float q6 = __shfl_xor(o6, 32), q7 = __shfl_xor(o7, 32);
        // k = 16s+0..7 from lh=0 lane; 16s+8..15 from lh=1 lane
        const float L0 = hihalf?q0:o0, L1 = hihalf?q1:o1, L2 = hihalf?q2:o2, L3 = hihalf?q3:o3;
        const float L4 = hihalf?q4:o4, L5 = hihalf?q5:o5, L6 = hihalf?q6:o6, L7 = hihalf?q7:o7;
        const float H0 = hihalf?o0:q0, H1 = hihalf?o1:q1, H2 = hihalf?o2:q2, H3 = hihalf?o3:q3;
        const float H4 = hihalf?o4:q4, H5 = hihalf?o5:q5, H6 = hihalf?o6:q6, H7 = hihalf?o7:q7;
        if (doA) {   // strict ascending-k BLAS chain, both lanes compute same result
          const float4 A0 = *(const float4*)(pa + s*16);
          const float4 A1 = *(const float4*)(pa + s*16 + 4);
          const float4 A2 = *(const float4*)(pa + s*16 + 8);
          const float4 A3 = *(const float4*)(pa + s*16 + 12);
          const float4 B0 = *(const float4*)(pb + s*16);
          const float4 B1 = *(const float4*)(pb + s*16 + 4);
          const float4 B2 = *(const float4*)(pb + s*16 + 8);
          const float4 B3 = *(const float4*)(pb + s*16 + 12);
          s1 = fmaf(L0,A0.x,s1); s1 = fmaf(L1,A0.y,s1); s1 = fmaf(L2,A0.z,s1); s1 = fmaf(L3,A0.w,s1);
          s1 = fmaf(L4,A1.x,s1); s1 = fmaf(L5,A1.y,s1); s1 = fmaf(L6,A1.z,s1); s1 = fmaf(L7,A1.w,s1);
          s1 = fmaf(H0,A2.x,s1); s1 = fmaf(H1,A2.y,s1); s1 = fmaf(H2,A2.z,s1); s1 = fmaf(H3,A2.w,s1);
          s1 = fmaf(H4,A3.x,s1); s1 = fmaf(H5,A3.y,s1); s1 = fmaf(H6,A3.z,s1); s1 = fmaf(H7,A3.w,s1);
          s2 = fmaf(L0,B0.x,s2); s2 = fmaf(L1,B0.y,s2); s2 = fmaf(L2,B0.z,s2); s2 = fmaf(L3,B0.w,s2);
          s2 = fmaf(L4,B1.x,s2); s2 = fmaf(L5,B1.y,s2); s2 = fmaf(L6,B1.z,s2); s2 = fmaf(L7,B1.w,s2);
          s2 = fmaf(H0,B2.x,s2); s2 = fmaf(H1,B2.y,s2); s2 = fmaf(H2,B2.z,s2); s2 = fmaf(H3,B2.w,s2);
          s2 = fmaf(H4,B3.x,s2); s2 = fmaf(H5,B3.y,s2); s2 = fmaf(H6,B3.z,s2); s2 = fmaf(H7,B3.w,s2);
        }
      }
      if (doA) {
        const float x2n = x2w[w][l31];
        const float d1 = __fsub_rn(__fadd_rn(x2n, y2l[cA1]), __fmul_rn(2.f, s1));
        const float d2 = __fsub_rn(__fadd_rn(x2n, y2l[cA2]), __fmul_rn(2.f, s2));
        const bool take2 = (d2 < d1) || (d2 == d1 && cA2 < cA1);
        if (lh == 0) rec[w][l31] = make_int2(take2 ? cA2 : cA1, 0);
      }
      asm volatile("s_waitcnt lgkmcnt(0)" ::: "memory");
    }

    // ---- phase 2b: mode B — wave-cooperative full scan (rare rows) ----
    if (wactive) {
      for (int ri = 0; ri < 32; ++ri) {
        const int2 rr2 = rec[w][ri];
        if ((rr2.x >> 12) != 2) continue;
        if (l31 == ri) {   // owning lanes stage the row from registers
          float* dst = &rs[w][lh*8];
#pragma unroll
          for (int s = 0; s < 8; ++s) {
            *(float4*)(dst + s*16)     = xa[s];
            *(float4*)(dst + s*16 + 4) = xb[s];
          }
        }
        asm volatile("s_waitcnt lgkmcnt(0)" ::: "memory");
        const float x2n = x2w[w][ri];
        float acc[16];
#pragma unroll
        for (int q = 0; q < 16; ++q) acc[q] = 0.f;
        for (int k = 0; k < 128; ++k) {       // ascending k: exact chain per j
          const float rv = rs[w][k];
          const float* cr = cbTl + (size_t)k*K_ + lane;
#pragma unroll
          for (int q = 0; q < 16; ++q)
            acc[q] = fmaf(rv, cr[q*64], acc[q]);
        }
        float vb = 3.0e38f; int jb = 0;
#pragma unroll
        for (int q = 0; q < 16; ++q) {
          const int j = q*64 + lane;
          const float dv = fmaf(-2.f, acc[q], __fadd_rn(x2n, y2l[j]));
          if (dv < vb) { vb = dv; jb = j; }   // ties keep lower (j ascends)
        }
#pragma unroll
        for (int off = 1; off < 64; off <<= 1) {
          const float bv = __shfl_xor(vb, off);
          const int   bj = __shfl_xor(jb, off);
          if (bv < vb || (bv == vb && bj < jb)) { vb = bv; jb = bj; }
        }
        if (lane == 0) rec[w][ri] = make_int2(jb, 0);
        asm volatile("s_waitcnt lgkmcnt(0)" ::: "memory");
      }
    }

    // ---- phase 3: in-register residual update + x2 + codes + loss ----
    if (wactive) {
      const int code = rec[w][l31].x & 1023;
      const float* cr = cbl + (size_t)code*D_ + lh*8;
      float4 qa[8], qb[8];
#pragma unroll
      for (int s = 0; s < 8; ++s) {
        qa[s] = *(const float4*)(cr + s*16);
        qb[s] = *(const float4*)(cr + s*16 + 4);
      }
      float rc[8] = {0,0,0,0,0,0,0,0};
#pragma unroll
      for (int s = 0; s < 8; ++s) {
        float rn[8];
        rn[0] = __fsub_rn(xa[s].x, qa[s].x); rn[1] = __fsub_rn(xa[s].y, qa[s].y);
        rn[2] = __fsub_rn(xa[s].z, qa[s].z); rn[3] = __fsub_rn(xa[s].w, qa[s].w);
        rn[4] = __fsub_rn(xb[s].x, qb[s].x); rn[5] = __fsub_rn(xb[s].y, qb[s].y);
        rn[6] = __fsub_rn(xb[s].z, qb[s].z); rn[7] = __fsub_rn(xb[s].w, qb[s].w);
        xa[s] = make_float4(rn[0], rn[1], rn[2], rn[3]);
        xb[s] = make_float4(rn[4], rn[5], rn[6], rn[7]);
#pragma unroll
        for (int c = 0; c < 8; ++c) lsum = fmaf(rn[c], rn[c], lsum);
#pragma unroll
        for (int c = 0; c < 8; ++c) {
          const float sq = __fmul_rn(rn[c], rn[c]);
          const float pv = __shfl_xor(sq, 32);
          rc[c] = __fadd_rn(rc[c], sq);
          rc[c] = __fadd_rn(rc[c], pv);
        }
      }
      if (lh == 0) {
        x2w[w][l31] = tree8(rc);
        out_codes[(size_t)l*N_ + row] = (float)code;
      }
    }
    asm volatile("s_waitcnt lgkmcnt(0)" ::: "memory");
  }

  // ---- write final residual back (only R write of the whole op) ----
  if (wactive) {
    float* rr = R + (size_t)row*D_ + lh*8;
#pragma unroll
    for (int s = 0; s < 8; ++s) {
      *(float4*)(rr + s*16)     = xa[s];
      *(float4*)(rr + s*16 + 4) = xb[s];
    }
  }
#pragma unroll
  for (int off = 1; off < 64; off <<= 1) lsum += __shfl_xor(lsum, off);
  if (wactive && lane == 0) atomicAdd(lossp, lsum);
}

// ---------------- finalize ----------------
__global__ __launch_bounds__(256)
void k_finalize_quant(const float* __restrict__ z, const float* __restrict__ R,
                      float* __restrict__ out) {
  __shared__ float tile[32][33];
  const int t0 = blockIdx.x * 32;
  const int d0 = blockIdx.y * 32;
  const int b  = blockIdx.z;
  const int tid = threadIdx.x;
  {
    const int ii = tid & 31; const int jj0 = (tid >> 5) * 4;
#pragma unroll
    for (int r = 0; r < 4; ++r) {
      const int jj = jj0 + r;
      tile[ii][jj] = (t0 + jj < T_) ? R[((size_t)(b*T_ + t0 + jj))*D_ + d0 + ii] : 0.f;
    }
  }
  __syncthreads();
  {
    const int jj = tid & 31; const int ii0 = (tid >> 5) * 4;
#pragma unroll
    for (int r = 0; r < 4; ++r) {
      const int ii = ii0 + r;
      if (t0 + jj < T_) {
        const size_t gi = ((size_t)(b*D_ + d0 + ii))*T_ + t0 + jj;
        out[gi] = __fsub_rn(z[gi], tile[ii][jj]);
      }
    }
  }
}

__global__ void k_finalize_loss(const float* __restrict__ lossp, float* __restrict__ out2) {
  const float lv = (float)((double)lossp[0] / (double)((size_t)N_ * D_));
  out2[0] = lv;
  out2[1] = lv;
}

// ---------------- host launch ----------------
extern "C" void kernel_launch(void* const* d_in, const int* in_sizes, int n_in,
                              void* d_out, int out_size, void* d_ws, size_t ws_size,
                              hipStream_t stream) {
  const float* z  = (const float*)d_in[0];
  const float* cb = (const float*)d_in[1];
  float* out = (float*)d_out;

  char* ws = (char*)d_ws;
  const size_t OFF_R    = 0;
  const size_t OFF_BPK  = OFF_R   + (size_t)N_ * D_ * 4;        // 36,864,000
  const size_t OFF_CBT  = OFF_BPK + (size_t)L_ * 16384 * 16;    // 38,961,152
  const size_t OFF_Y2   = OFF_CBT + (size_t)L_ * D_ * K_ * 4;   // 43,155,456
  const size_t OFF_LOSS = OFF_Y2  + (size_t)L_ * K_ * 4;        // 43,188,224

  float* R     = (float*)(ws + OFF_R);
  uint4* Bpk   = (uint4*)(ws + OFF_BPK);
  float* cbT   = (float*)(ws + OFF_CBT);
  float* y2f   = (float*)(ws + OFF_Y2);
  float* lossp = (float*)(ws + OFF_LOSS);

  hipMemsetAsync(lossp, 0, 4, stream);

  k_transpose_z<<<dim3((T_ + 31)/32, D_/32, B_), 256, 0, stream>>>(z, R);
  k_transpose_cb<<<dim3(K_/32, D_/32, L_), 256, 0, stream>>>(cb, cbT);
  k_y2<<<(L_ * K_)/256, 256, 0, stream>>>(cb, y2f);
  k_prep_b<<<64, 256, 0, stream>>>(cb, Bpk);

  k_rvq<<<NBLK, 256, 0, stream>>>(R, Bpk, y2f, cb, cbT,
                                  out + (size_t)N_ * D_, lossp);

  k_finalize_quant<<<dim3((T_ + 31)/32, D_/32, B_), 256, 0, stream>>>(z, R, out);
  k_finalize_loss<<<1, 1, 0, stream>>>(lossp, out + (size_t)N_ * D_ + (size_t)L_ * N_);
}